// Round 20
// baseline (281.274 us; speedup 1.0000x reference)
//
#include <hip/hip_runtime.h>
#include <hip/hip_bf16.h>
#include <stdint.h>

// GPTQ 4-bit linear: y = x @ dequant(qweight,qzeros,scales) + bias
// x: [4,2048,4096] fp32 -> M=8192 rows; qweight [512,4096] i32 (8 k-nibbles/word);
// qzeros [32,512] i32 (8 n-nibbles/word, z=nib+1); scales [32,4096] f32; out f32.

#define M_TOT 8192
#define N_TOT 4096
#define K_TOT 4096
#define NT    (K_TOT / 64)   // 64 K-tiles of BK=64

using bf16x8 = __attribute__((ext_vector_type(8))) __bf16;
using f32x4  = __attribute__((ext_vector_type(4))) float;

__device__ __forceinline__ unsigned short f2bf(float f) {
  unsigned u = __builtin_bit_cast(unsigned, f);
  u += 0x7fffu + ((u >> 16) & 1u);   // RNE
  return (unsigned short)(u >> 16);
}

// ---------------- x: fp32 -> bf16 (BW-floor, frozen) ----------------
__global__ void cvt_x_kernel(const float* __restrict__ x,
                             unsigned short* __restrict__ xb, int n) {
  int stride = gridDim.x * blockDim.x * 8;
  for (int i = (blockIdx.x * blockDim.x + threadIdx.x) * 8; i < n; i += stride) {
    float4 a = *reinterpret_cast<const float4*>(x + i);
    float4 b = *reinterpret_cast<const float4*>(x + i + 4);
    unsigned short o[8] = {f2bf(a.x), f2bf(a.y), f2bf(a.z), f2bf(a.w),
                           f2bf(b.x), f2bf(b.y), f2bf(b.z), f2bf(b.w)};
    *reinterpret_cast<uint4*>(xb + i) = *reinterpret_cast<const uint4*>(o);
  }
}

// ---- dequant -> W^T [N][K] bf16, LDS-transposed (r19-verified, frozen) -----
__global__ __launch_bounds__(256) void dequant_lds_kernel(
    const int* __restrict__ qweight, const int* __restrict__ qzeros,
    const float* __restrict__ scales, unsigned short* __restrict__ wt) {
  __shared__ int      lw[16][65];   // +1 pad: conflict-free transposed reads
  __shared__ float    lsc[64];
  __shared__ unsigned lzw[8];

  int db = blockIdx.x;              // 2048 blocks: 32 kw-tiles x 64 nn-tiles
  int kt = db >> 6, nt = db & 63;
  int kw0 = kt * 16, nn0 = nt * 64;
  int tau = threadIdx.x;

  int col = tau & 63, rowb = tau >> 6;       // rowb 0..3
#pragma unroll
  for (int r = 0; r < 4; ++r)
    lw[rowb + r * 4][col] = qweight[(kw0 + rowb + r * 4) * N_TOT + nn0 + col];
  int g = kt;                                // group = kw0/16 (GROUPSIZE 128)
  if (tau < 64) lsc[tau] = scales[g * N_TOT + nn0 + tau];
  if (tau < 8)  lzw[tau] = (unsigned)qzeros[g * (N_TOT / 8) + (nn0 >> 3) + tau];
  __syncthreads();

  int kwc = tau & 15, grp = tau >> 4;        // grp 0..15
#pragma unroll
  for (int j = 0; j < 4; ++j) {
    int nnr = grp * 4 + j;                   // 0..63
    unsigned w = (unsigned)lw[kwc][nnr];
    float sc = lsc[nnr];
    unsigned zw = lzw[nnr >> 3];
    float zs = sc * (float)(((zw >> ((nnr & 7) * 4)) & 15u) + 1u);
    unsigned short o[8];
#pragma unroll
    for (int jj = 0; jj < 8; ++jj) {
      float v = sc * (float)((w >> (4 * jj)) & 15u) - zs;
      o[jj] = f2bf(v);
    }
    *reinterpret_cast<uint4*>(wt + (size_t)(nn0 + nnr) * K_TOT +
                              (kw0 + kwc) * 8) =
        *reinterpret_cast<const uint4*>(o);
  }
}

// -- 256x256 GEMM, 1-barrier/tile: all stages at q3-top, 3+ phases ahead -----
// q2-end = the single sync point: lgkm(0) proves A(t)-reads done (legalizes
// q3-top A(t+2) restage), vmcnt(0) drains A/B(t+1) issued 3+ phases back
// (free), barrier publishes; cross-reads follow. q3-end barrier removed.
__device__ __forceinline__ void gll16(const unsigned short* g, const unsigned short* l) {
  __builtin_amdgcn_global_load_lds(
      (const __attribute__((address_space(1))) void*)(uintptr_t)g,
      (__attribute__((address_space(3))) void*)(uintptr_t)l, 16, 0, 0);
}

__global__ __launch_bounds__(512, 2) void gemm_1bar_kernel(
    const unsigned short* __restrict__ A,   // [M_TOT][K_TOT] bf16
    const unsigned short* __restrict__ B,   // [N_TOT][K_TOT] bf16 (W^T)
    const float* __restrict__ bias,
    float* __restrict__ C) {
  __shared__ __align__(16) unsigned short As[2 * 256 * 64];   // 64 KB
  __shared__ __align__(16) unsigned short Bs[2 * 256 * 64];   // 64 KB

  int bid = blockIdx.x;                    // 512 blocks, 512 % 8 == 0
  int swz = (bid & 7) * 64 + (bid >> 3);   // bijective XCD swizzle (T1)
  int bm = swz & 31, bn = swz >> 5;        // 32 x 16 tiles
  int m0 = bm * 256, n0 = bn * 256;

  int t = threadIdx.x;
  int lane = t & 63;
  int wave = t >> 6;                       // 8 waves
  int wr = wave >> 2, wc = wave & 3;       // 2 (M) x 4 (N)
  int lr = lane & 15, kq = lane >> 4;

  // Staging (round-3 verified, 0 conflicts): physical chunk p = t&7 of rows
  // rowL0, rowL0+64; source pre-permuted j_log = (t&7) ^ (rowL0&7).
  int rowL0 = t >> 3;
  int jlog  = ((t & 7) ^ (rowL0 & 7)) * 8;
  const unsigned short* aG = A + (size_t)(m0 + rowL0) * K_TOT + jlog;
  const unsigned short* bG = B + (size_t)(n0 + rowL0) * K_TOT + jlog;

  // Swizzled read bases; s half-select composed with XOR (round-2 lesson).
  unsigned rbA = (unsigned)((wr * 128 + lr) * 128 + ((kq * 16) ^ ((lr & 7) << 4)));
  unsigned rbB = (unsigned)((wc * 64  + lr) * 128 + ((kq * 16) ^ ((lr & 7) << 4)));

  f32x4 acc[8][4] = {};
  bf16x8 av[2][2][2];   // [pingpong][mm][s]
  bf16x8 bh[2][4][2];   // [tile parity][n][s]

#define STAGE(matG, ldsArr, tile, h)                                              \
  do {                                                                            \
    const unsigned short* _g = (matG) + (size_t)(h) * 128 * K_TOT +               \
                               (size_t)(tile) * 64;                               \
    const unsigned short* _l = (ldsArr) + ((tile) & 1) * 16384 + (h) * 8192 +     \
                               t * 8;                                             \
    gll16(_g, _l);                                                                \
    gll16(_g + (size_t)64 * K_TOT, _l + 4096);                                    \
  } while (0)

  // Prologue: A(0),B(0) (8 oldest glls), then A(1),B(1).
  STAGE(aG, As, 0, 0);
  STAGE(aG, As, 0, 1);
  STAGE(bG, Bs, 0, 0);
  STAGE(bG, Bs, 0, 1);
  STAGE(aG, As, 1, 0);
  STAGE(aG, As, 1, 1);
  STAGE(bG, Bs, 1, 0);
  STAGE(bG, Bs, 1, 1);
  asm volatile("s_waitcnt vmcnt(8)" ::: "memory");  // A(0),B(0) landed
  __builtin_amdgcn_s_barrier();
  __builtin_amdgcn_sched_barrier(0);

  // Preload tile-0 operands: bh[0] = B(0), av[0] = A(0) phase-0 frags.
  {
    const char* aB0 = (const char*)As;
    const char* bB0 = (const char*)Bs;
#pragma unroll
    for (int n = 0; n < 4; ++n)
#pragma unroll
      for (int s = 0; s < 2; ++s)
        bh[0][n][s] = *(const bf16x8*)(bB0 + ((rbB + n * 2048) ^ (s * 64)));
#pragma unroll
    for (int mm = 0; mm < 2; ++mm)
#pragma unroll
      for (int s = 0; s < 2; ++s)
        av[0][mm][s] = *(const bf16x8*)(aB0 + ((rbA + mm * 2048) ^ (s * 64)));
  }

#pragma unroll 2
  for (int tt = 0; tt < NT; ++tt) {
    const char* aBuf = (const char*)As + (tt & 1) * 32768;

#pragma unroll
    for (int q = 0; q < 4; ++q) {
      // --- q3-top: stage tile t+2 (A then B), 3+ phases before their drain.
      // WAR-safe: q2-end lgkm(0)+barrier proved all waves' A(t)-prefetch
      // reads completed (A region) and all bh(t) reads long done (B region).
      if (q == 3 && tt + 2 < NT) {
        STAGE(aG, As, tt + 2, 0);
        STAGE(aG, As, tt + 2, 1);
        STAGE(bG, Bs, tt + 2, 0);
        STAGE(bG, Bs, tt + 2, 1);
      }

      // --- MFMA on operands issued >= 1 phase ago ---
      __builtin_amdgcn_s_setprio(1);
#pragma unroll
      for (int s = 0; s < 2; ++s)
#pragma unroll
        for (int mm = 0; mm < 2; ++mm)
#pragma unroll
          for (int n = 0; n < 4; ++n)
            acc[2 * q + mm][n] = __builtin_amdgcn_mfma_f32_16x16x32_bf16(
                av[q & 1][mm][s], bh[tt & 1][n][s], acc[2 * q + mm][n], 0, 0, 0);
      __builtin_amdgcn_s_setprio(0);

      // --- prefetch next phase's A frags (parity t; stages write parity !t) --
      if (q < 3) {
#pragma unroll
        for (int mm = 0; mm < 2; ++mm)
#pragma unroll
          for (int s = 0; s < 2; ++s)
            av[(q + 1) & 1][mm][s] = *(const bf16x8*)(
                aBuf + ((rbA + (2 * (q + 1) + mm) * 2048) ^ (s * 64)));
      }

      if (q == 2) {
        // THE single sync point per tile.
        // lgkm(0): all this wave's ds_reads (incl. q2's av[1] prefetch)
        // complete -> legalizes q3-top A(t+2) restage after the barrier.
        // vmcnt(0): drains A(t+1)/B(t+1), issued q3-top of t-1 (~3.5 phases,
        // ~2200 cyc ago) -> effectively free.
        asm volatile("s_waitcnt lgkmcnt(0)" ::: "memory");
        asm volatile("s_waitcnt vmcnt(0)" ::: "memory");
        __builtin_amdgcn_s_barrier();
        __builtin_amdgcn_sched_barrier(0);
        if (tt + 1 < NT) {                   // cross-tile operand preload
          const char* aN = (const char*)As + ((tt + 1) & 1) * 32768;
          const char* bN = (const char*)Bs + ((tt + 1) & 1) * 32768;
#pragma unroll
          for (int n = 0; n < 4; ++n)
#pragma unroll
            for (int s = 0; s < 2; ++s)
              bh[(tt + 1) & 1][n][s] =
                  *(const bf16x8*)(bN + ((rbB + n * 2048) ^ (s * 64)));
#pragma unroll
          for (int mm = 0; mm < 2; ++mm)
#pragma unroll
            for (int s = 0; s < 2; ++s)
              av[0][mm][s] = *(const bf16x8*)(aN + ((rbA + mm * 2048) ^ (s * 64)));
        }
        __builtin_amdgcn_sched_barrier(0);
      }
    }
  }
#undef STAGE

  // Epilogue: C/D layout col=lane&15, row=(lane>>4)*4+reg (m89-verified).
#pragma unroll
  for (int n = 0; n < 4; ++n) {
    int ncol = n0 + wc * 64 + n * 16 + lr;
    float bz = bias[ncol];
#pragma unroll
    for (int m = 0; m < 8; ++m) {
      int mrow = m0 + wr * 128 + m * 16 + kq * 4;
#pragma unroll
      for (int r = 0; r < 4; ++r)
        C[(size_t)(mrow + r) * N_TOT + ncol] = acc[m][n][r] + bz;
    }
  }
}

extern "C" void kernel_launch(void* const* d_in, const int* in_sizes, int n_in,
                              void* d_out, int out_size, void* d_ws, size_t ws_size,
                              hipStream_t stream) {
  const float* x       = (const float*)d_in[0];
  const int*   qweight = (const int*)d_in[1];
  const int*   qzeros  = (const int*)d_in[2];
  const float* scales  = (const float*)d_in[3];
  const float* bias    = (const float*)d_in[4];
  float* out = (float*)d_out;

  const size_t xb_bytes = (size_t)M_TOT * K_TOT * 2;   // 64 MB
  const size_t wt_bytes = (size_t)N_TOT * K_TOT * 2;   // 32 MB
  if (ws_size < xb_bytes + wt_bytes) return;

  unsigned short* Xb = (unsigned short*)d_ws;
  unsigned short* Wt = (unsigned short*)((char*)d_ws + xb_bytes);

  cvt_x_kernel<<<2048, 256, 0, stream>>>(x, Xb, M_TOT * K_TOT);
  dequant_lds_kernel<<<2048, 256, 0, stream>>>(qweight, qzeros, scales, Wt);

  dim3 grid((M_TOT / 256) * (N_TOT / 256));  // 512
  gemm_1bar_kernel<<<grid, 512, 0, stream>>>(Xb, Wt, bias, out);
}

// Round 21
// 271.125 us; speedup vs baseline: 1.0374x; 1.0374x over previous
//
#include <hip/hip_runtime.h>
#include <hip/hip_bf16.h>
#include <stdint.h>

// GPTQ 4-bit linear: y = x @ dequant(qweight,qzeros,scales) + bias
// x: [4,2048,4096] fp32 -> M=8192 rows; qweight [512,4096] i32 (8 k-nibbles/word);
// qzeros [32,512] i32 (8 n-nibbles/word, z=nib+1); scales [32,4096] f32; out f32.
//
// FINAL CONFIGURATION (= round-19 measured champion, 271.4 us):
//   cvt_x (BW-floor) + dequant_lds (coalesced) + gemm_hoist (r17, 52.9% MfmaUtil).

#define M_TOT 8192
#define N_TOT 4096
#define K_TOT 4096
#define NT    (K_TOT / 64)   // 64 K-tiles of BK=64

using bf16x8 = __attribute__((ext_vector_type(8))) __bf16;
using f32x4  = __attribute__((ext_vector_type(4))) float;

__device__ __forceinline__ unsigned short f2bf(float f) {
  unsigned u = __builtin_bit_cast(unsigned, f);
  u += 0x7fffu + ((u >> 16) & 1u);   // RNE
  return (unsigned short)(u >> 16);
}

// ---------------- x: fp32 -> bf16 (BW-floor, frozen) ----------------
__global__ void cvt_x_kernel(const float* __restrict__ x,
                             unsigned short* __restrict__ xb, int n) {
  int stride = gridDim.x * blockDim.x * 8;
  for (int i = (blockIdx.x * blockDim.x + threadIdx.x) * 8; i < n; i += stride) {
    float4 a = *reinterpret_cast<const float4*>(x + i);
    float4 b = *reinterpret_cast<const float4*>(x + i + 4);
    unsigned short o[8] = {f2bf(a.x), f2bf(a.y), f2bf(a.z), f2bf(a.w),
                           f2bf(b.x), f2bf(b.y), f2bf(b.z), f2bf(b.w)};
    *reinterpret_cast<uint4*>(xb + i) = *reinterpret_cast<const uint4*>(o);
  }
}

// ---- dequant -> W^T [N][K] bf16, LDS-transposed (r19-verified, frozen) -----
__global__ __launch_bounds__(256) void dequant_lds_kernel(
    const int* __restrict__ qweight, const int* __restrict__ qzeros,
    const float* __restrict__ scales, unsigned short* __restrict__ wt) {
  __shared__ int      lw[16][65];   // +1 pad: conflict-free transposed reads
  __shared__ float    lsc[64];
  __shared__ unsigned lzw[8];

  int db = blockIdx.x;              // 2048 blocks: 32 kw-tiles x 64 nn-tiles
  int kt = db >> 6, nt = db & 63;
  int kw0 = kt * 16, nn0 = nt * 64;
  int tau = threadIdx.x;

  int col = tau & 63, rowb = tau >> 6;       // rowb 0..3
#pragma unroll
  for (int r = 0; r < 4; ++r)
    lw[rowb + r * 4][col] = qweight[(kw0 + rowb + r * 4) * N_TOT + nn0 + col];
  int g = kt;                                // group = kw0/16 (GROUPSIZE 128)
  if (tau < 64) lsc[tau] = scales[g * N_TOT + nn0 + tau];
  if (tau < 8)  lzw[tau] = (unsigned)qzeros[g * (N_TOT / 8) + (nn0 >> 3) + tau];
  __syncthreads();

  int kwc = tau & 15, grp = tau >> 4;        // grp 0..15
#pragma unroll
  for (int j = 0; j < 4; ++j) {
    int nnr = grp * 4 + j;                   // 0..63
    unsigned w = (unsigned)lw[kwc][nnr];
    float sc = lsc[nnr];
    unsigned zw = lzw[nnr >> 3];
    float zs = sc * (float)(((zw >> ((nnr & 7) * 4)) & 15u) + 1u);
    unsigned short o[8];
#pragma unroll
    for (int jj = 0; jj < 8; ++jj) {
      float v = sc * (float)((w >> (4 * jj)) & 15u) - zs;
      o[jj] = f2bf(v);
    }
    *reinterpret_cast<uint4*>(wt + (size_t)(nn0 + nnr) * K_TOT +
                              (kw0 + kwc) * 8) =
        *reinterpret_cast<const uint4*>(o);
  }
}

// -- 256x256 GEMM (round-17 champion, FROZEN): barriers q2-end/q3-end; next-
// tile operand reads issue at q2-end and hide under q3's MFMA cluster. -------
__device__ __forceinline__ void gll16(const unsigned short* g, const unsigned short* l) {
  __builtin_amdgcn_global_load_lds(
      (const __attribute__((address_space(1))) void*)(uintptr_t)g,
      (__attribute__((address_space(3))) void*)(uintptr_t)l, 16, 0, 0);
}

__global__ __launch_bounds__(512, 2) void gemm_hoist_kernel(
    const unsigned short* __restrict__ A,   // [M_TOT][K_TOT] bf16
    const unsigned short* __restrict__ B,   // [N_TOT][K_TOT] bf16 (W^T)
    const float* __restrict__ bias,
    float* __restrict__ C) {
  __shared__ __align__(16) unsigned short As[2 * 256 * 64];   // 64 KB
  __shared__ __align__(16) unsigned short Bs[2 * 256 * 64];   // 64 KB

  int bid = blockIdx.x;                    // 512 blocks, 512 % 8 == 0
  int swz = (bid & 7) * 64 + (bid >> 3);   // bijective XCD swizzle (T1)
  int bm = swz & 31, bn = swz >> 5;        // 32 x 16 tiles
  int m0 = bm * 256, n0 = bn * 256;

  int t = threadIdx.x;
  int lane = t & 63;
  int wave = t >> 6;                       // 8 waves
  int wr = wave >> 2, wc = wave & 3;       // 2 (M) x 4 (N)
  int lr = lane & 15, kq = lane >> 4;

  // Staging (round-3 verified, 0 conflicts): physical chunk p = t&7 of rows
  // rowL0, rowL0+64; source pre-permuted j_log = (t&7) ^ (rowL0&7).
  int rowL0 = t >> 3;
  int jlog  = ((t & 7) ^ (rowL0 & 7)) * 8;
  const unsigned short* aG = A + (size_t)(m0 + rowL0) * K_TOT + jlog;
  const unsigned short* bG = B + (size_t)(n0 + rowL0) * K_TOT + jlog;

  // Swizzled read bases; s half-select composed with XOR (round-2 lesson).
  unsigned rbA = (unsigned)((wr * 128 + lr) * 128 + ((kq * 16) ^ ((lr & 7) << 4)));
  unsigned rbB = (unsigned)((wc * 64  + lr) * 128 + ((kq * 16) ^ ((lr & 7) << 4)));

  f32x4 acc[8][4] = {};
  bf16x8 av[2][2][2];   // [pingpong][mm][s]
  bf16x8 bh[2][4][2];   // [tile parity][n][s]

#define STAGE(matG, ldsArr, tile, h)                                              \
  do {                                                                            \
    const unsigned short* _g = (matG) + (size_t)(h) * 128 * K_TOT +               \
                               (size_t)(tile) * 64;                               \
    const unsigned short* _l = (ldsArr) + ((tile) & 1) * 16384 + (h) * 8192 +     \
                               t * 8;                                             \
    gll16(_g, _l);                                                                \
    gll16(_g + (size_t)64 * K_TOT, _l + 4096);                                    \
  } while (0)

  // Prologue: A(0):4, B(0):4, B(1):4 glls. A(1) stages at tile-0 q0.
  STAGE(aG, As, 0, 0);
  STAGE(aG, As, 0, 1);
  STAGE(bG, Bs, 0, 0);
  STAGE(bG, Bs, 0, 1);
  STAGE(bG, Bs, 1, 0);
  STAGE(bG, Bs, 1, 1);
  asm volatile("s_waitcnt vmcnt(4)" ::: "memory");  // A(0),B(0) landed
  __builtin_amdgcn_s_barrier();
  __builtin_amdgcn_sched_barrier(0);

  // Preload tile-0 operands: bh[0] = B(0), av[0] = A(0) phase-0 frags.
  {
    const char* aB0 = (const char*)As;
    const char* bB0 = (const char*)Bs;
#pragma unroll
    for (int n = 0; n < 4; ++n)
#pragma unroll
      for (int s = 0; s < 2; ++s)
        bh[0][n][s] = *(const bf16x8*)(bB0 + ((rbB + n * 2048) ^ (s * 64)));
#pragma unroll
    for (int mm = 0; mm < 2; ++mm)
#pragma unroll
      for (int s = 0; s < 2; ++s)
        av[0][mm][s] = *(const bf16x8*)(aB0 + ((rbA + mm * 2048) ^ (s * 64)));
  }

#pragma unroll 2
  for (int tt = 0; tt < NT; ++tt) {
    const char* aBuf = (const char*)As + (tt & 1) * 32768;

#pragma unroll
    for (int q = 0; q < 4; ++q) {
      // --- MFMA on operands issued >= 1 phase ago ---
      __builtin_amdgcn_s_setprio(1);
#pragma unroll
      for (int s = 0; s < 2; ++s)
#pragma unroll
        for (int mm = 0; mm < 2; ++mm)
#pragma unroll
          for (int n = 0; n < 4; ++n)
            acc[2 * q + mm][n] = __builtin_amdgcn_mfma_f32_16x16x32_bf16(
                av[q & 1][mm][s], bh[tt & 1][n][s], acc[2 * q + mm][n], 0, 0, 0);
      __builtin_amdgcn_s_setprio(0);

      // --- stage A(t+1) both halves at q0 (WAR-safe: q3-end barrier of t-1
      // proved all waves consumed their av(t-1) reads) ---
      if (q == 0 && tt + 1 < NT) {
        STAGE(aG, As, tt + 1, 0);
        STAGE(aG, As, tt + 1, 1);
      }

      // --- prefetch next phase's A frags (same parity; stages write other) ---
      if (q < 3) {
#pragma unroll
        for (int mm = 0; mm < 2; ++mm)
#pragma unroll
          for (int s = 0; s < 2; ++s)
            av[(q + 1) & 1][mm][s] = *(const bf16x8*)(
                aBuf + ((rbA + (2 * (q + 1) + mm) * 2048) ^ (s * 64)));
      }

      if (q == 2) {
        // q2-end checkpoint: drain B(t+1) (issued t-1 q3) and A(t+1) (q0) ->
        // both older than HBM latency. Barrier publishes; cross-reads issue
        // HERE and hide under q3's MFMA.
        asm volatile("s_waitcnt vmcnt(0)" ::: "memory");
        __builtin_amdgcn_s_barrier();
        __builtin_amdgcn_sched_barrier(0);
        if (tt + 1 < NT) {
          const char* aN = (const char*)As + ((tt + 1) & 1) * 32768;
          const char* bN = (const char*)Bs + ((tt + 1) & 1) * 32768;
#pragma unroll
          for (int n = 0; n < 4; ++n)
#pragma unroll
            for (int s = 0; s < 2; ++s)
              bh[(tt + 1) & 1][n][s] =
                  *(const bf16x8*)(bN + ((rbB + n * 2048) ^ (s * 64)));
#pragma unroll
          for (int mm = 0; mm < 2; ++mm)
#pragma unroll
            for (int s = 0; s < 2; ++s)
              av[0][mm][s] = *(const bf16x8*)(aN + ((rbA + mm * 2048) ^ (s * 64)));
        }
      }

      if (q == 3) {
        // Stage B(t+2) both halves: q2-end barrier proved all waves executed
        // q0 -> every bh(t) read completed -> overwriting B parity is safe.
        if (tt + 2 < NT) {
          STAGE(bG, Bs, tt + 2, 0);
          STAGE(bG, Bs, tt + 2, 1);
        }
        __builtin_amdgcn_s_barrier();   // q3-end: closes the tile
      }
    }
  }
#undef STAGE

  // Epilogue: C/D layout col=lane&15, row=(lane>>4)*4+reg (m89-verified).
#pragma unroll
  for (int n = 0; n < 4; ++n) {
    int ncol = n0 + wc * 64 + n * 16 + lr;
    float bz = bias[ncol];
#pragma unroll
    for (int m = 0; m < 8; ++m) {
      int mrow = m0 + wr * 128 + m * 16 + kq * 4;
#pragma unroll
      for (int r = 0; r < 4; ++r)
        C[(size_t)(mrow + r) * N_TOT + ncol] = acc[m][n][r] + bz;
    }
  }
}

extern "C" void kernel_launch(void* const* d_in, const int* in_sizes, int n_in,
                              void* d_out, int out_size, void* d_ws, size_t ws_size,
                              hipStream_t stream) {
  const float* x       = (const float*)d_in[0];
  const int*   qweight = (const int*)d_in[1];
  const int*   qzeros  = (const int*)d_in[2];
  const float* scales  = (const float*)d_in[3];
  const float* bias    = (const float*)d_in[4];
  float* out = (float*)d_out;

  const size_t xb_bytes = (size_t)M_TOT * K_TOT * 2;   // 64 MB
  const size_t wt_bytes = (size_t)N_TOT * K_TOT * 2;   // 32 MB
  if (ws_size < xb_bytes + wt_bytes) return;

  unsigned short* Xb = (unsigned short*)d_ws;
  unsigned short* Wt = (unsigned short*)((char*)d_ws + xb_bytes);

  cvt_x_kernel<<<2048, 256, 0, stream>>>(x, Xb, M_TOT * K_TOT);
  dequant_lds_kernel<<<2048, 256, 0, stream>>>(qweight, qzeros, scales, Wt);

  dim3 grid((M_TOT / 256) * (N_TOT / 256));  // 512
  gemm_hoist_kernel<<<grid, 512, 0, stream>>>(Xb, Wt, bias, out);
}

// Round 22
// 268.270 us; speedup vs baseline: 1.0485x; 1.0106x over previous
//
#include <hip/hip_runtime.h>
#include <hip/hip_bf16.h>
#include <stdint.h>

// GPTQ 4-bit linear: y = x @ dequant(qweight,qzeros,scales) + bias
// x: [4,2048,4096] fp32 -> M=8192 rows; qweight [512,4096] i32 (8 k-nibbles/word);
// qzeros [32,512] i32 (8 n-nibbles/word, z=nib+1); scales [32,4096] f32; out f32.
//
// Configuration = round-19/21 champion (271.2 us reproduced), with s_setprio
// removed from the MFMA cluster (m190: setprio hurts lockstep GEMM; T5 pays
// only on role-split 8-phase schedules, which this is not).

#define M_TOT 8192
#define N_TOT 4096
#define K_TOT 4096
#define NT    (K_TOT / 64)   // 64 K-tiles of BK=64

using bf16x8 = __attribute__((ext_vector_type(8))) __bf16;
using f32x4  = __attribute__((ext_vector_type(4))) float;

__device__ __forceinline__ unsigned short f2bf(float f) {
  unsigned u = __builtin_bit_cast(unsigned, f);
  u += 0x7fffu + ((u >> 16) & 1u);   // RNE
  return (unsigned short)(u >> 16);
}

// ---------------- x: fp32 -> bf16 (BW-floor, frozen) ----------------
__global__ void cvt_x_kernel(const float* __restrict__ x,
                             unsigned short* __restrict__ xb, int n) {
  int stride = gridDim.x * blockDim.x * 8;
  for (int i = (blockIdx.x * blockDim.x + threadIdx.x) * 8; i < n; i += stride) {
    float4 a = *reinterpret_cast<const float4*>(x + i);
    float4 b = *reinterpret_cast<const float4*>(x + i + 4);
    unsigned short o[8] = {f2bf(a.x), f2bf(a.y), f2bf(a.z), f2bf(a.w),
                           f2bf(b.x), f2bf(b.y), f2bf(b.z), f2bf(b.w)};
    *reinterpret_cast<uint4*>(xb + i) = *reinterpret_cast<const uint4*>(o);
  }
}

// ---- dequant -> W^T [N][K] bf16, LDS-transposed (r19-verified, frozen) -----
__global__ __launch_bounds__(256) void dequant_lds_kernel(
    const int* __restrict__ qweight, const int* __restrict__ qzeros,
    const float* __restrict__ scales, unsigned short* __restrict__ wt) {
  __shared__ int      lw[16][65];   // +1 pad: conflict-free transposed reads
  __shared__ float    lsc[64];
  __shared__ unsigned lzw[8];

  int db = blockIdx.x;              // 2048 blocks: 32 kw-tiles x 64 nn-tiles
  int kt = db >> 6, nt = db & 63;
  int kw0 = kt * 16, nn0 = nt * 64;
  int tau = threadIdx.x;

  int col = tau & 63, rowb = tau >> 6;       // rowb 0..3
#pragma unroll
  for (int r = 0; r < 4; ++r)
    lw[rowb + r * 4][col] = qweight[(kw0 + rowb + r * 4) * N_TOT + nn0 + col];
  int g = kt;                                // group = kw0/16 (GROUPSIZE 128)
  if (tau < 64) lsc[tau] = scales[g * N_TOT + nn0 + tau];
  if (tau < 8)  lzw[tau] = (unsigned)qzeros[g * (N_TOT / 8) + (nn0 >> 3) + tau];
  __syncthreads();

  int kwc = tau & 15, grp = tau >> 4;        // grp 0..15
#pragma unroll
  for (int j = 0; j < 4; ++j) {
    int nnr = grp * 4 + j;                   // 0..63
    unsigned w = (unsigned)lw[kwc][nnr];
    float sc = lsc[nnr];
    unsigned zw = lzw[nnr >> 3];
    float zs = sc * (float)(((zw >> ((nnr & 7) * 4)) & 15u) + 1u);
    unsigned short o[8];
#pragma unroll
    for (int jj = 0; jj < 8; ++jj) {
      float v = sc * (float)((w >> (4 * jj)) & 15u) - zs;
      o[jj] = f2bf(v);
    }
    *reinterpret_cast<uint4*>(wt + (size_t)(nn0 + nnr) * K_TOT +
                              (kw0 + kwc) * 8) =
        *reinterpret_cast<const uint4*>(o);
  }
}

// -- 256x256 GEMM (r17 champion; setprio removed): barriers q2-end/q3-end;
// next-tile operand reads issue at q2-end and hide under q3's MFMA cluster. --
__device__ __forceinline__ void gll16(const unsigned short* g, const unsigned short* l) {
  __builtin_amdgcn_global_load_lds(
      (const __attribute__((address_space(1))) void*)(uintptr_t)g,
      (__attribute__((address_space(3))) void*)(uintptr_t)l, 16, 0, 0);
}

__global__ __launch_bounds__(512, 2) void gemm_hoist_kernel(
    const unsigned short* __restrict__ A,   // [M_TOT][K_TOT] bf16
    const unsigned short* __restrict__ B,   // [N_TOT][K_TOT] bf16 (W^T)
    const float* __restrict__ bias,
    float* __restrict__ C) {
  __shared__ __align__(16) unsigned short As[2 * 256 * 64];   // 64 KB
  __shared__ __align__(16) unsigned short Bs[2 * 256 * 64];   // 64 KB

  int bid = blockIdx.x;                    // 512 blocks, 512 % 8 == 0
  int swz = (bid & 7) * 64 + (bid >> 3);   // bijective XCD swizzle (T1)
  int bm = swz & 31, bn = swz >> 5;        // 32 x 16 tiles
  int m0 = bm * 256, n0 = bn * 256;

  int t = threadIdx.x;
  int lane = t & 63;
  int wave = t >> 6;                       // 8 waves
  int wr = wave >> 2, wc = wave & 3;       // 2 (M) x 4 (N)
  int lr = lane & 15, kq = lane >> 4;

  // Staging (round-3 verified, 0 conflicts): physical chunk p = t&7 of rows
  // rowL0, rowL0+64; source pre-permuted j_log = (t&7) ^ (rowL0&7).
  int rowL0 = t >> 3;
  int jlog  = ((t & 7) ^ (rowL0 & 7)) * 8;
  const unsigned short* aG = A + (size_t)(m0 + rowL0) * K_TOT + jlog;
  const unsigned short* bG = B + (size_t)(n0 + rowL0) * K_TOT + jlog;

  // Swizzled read bases; s half-select composed with XOR (round-2 lesson).
  unsigned rbA = (unsigned)((wr * 128 + lr) * 128 + ((kq * 16) ^ ((lr & 7) << 4)));
  unsigned rbB = (unsigned)((wc * 64  + lr) * 128 + ((kq * 16) ^ ((lr & 7) << 4)));

  f32x4 acc[8][4] = {};
  bf16x8 av[2][2][2];   // [pingpong][mm][s]
  bf16x8 bh[2][4][2];   // [tile parity][n][s]

#define STAGE(matG, ldsArr, tile, h)                                              \
  do {                                                                            \
    const unsigned short* _g = (matG) + (size_t)(h) * 128 * K_TOT +               \
                               (size_t)(tile) * 64;                               \
    const unsigned short* _l = (ldsArr) + ((tile) & 1) * 16384 + (h) * 8192 +     \
                               t * 8;                                             \
    gll16(_g, _l);                                                                \
    gll16(_g + (size_t)64 * K_TOT, _l + 4096);                                    \
  } while (0)

  // Prologue: A(0):4, B(0):4, B(1):4 glls. A(1) stages at tile-0 q0.
  STAGE(aG, As, 0, 0);
  STAGE(aG, As, 0, 1);
  STAGE(bG, Bs, 0, 0);
  STAGE(bG, Bs, 0, 1);
  STAGE(bG, Bs, 1, 0);
  STAGE(bG, Bs, 1, 1);
  asm volatile("s_waitcnt vmcnt(4)" ::: "memory");  // A(0),B(0) landed
  __builtin_amdgcn_s_barrier();
  __builtin_amdgcn_sched_barrier(0);

  // Preload tile-0 operands: bh[0] = B(0), av[0] = A(0) phase-0 frags.
  {
    const char* aB0 = (const char*)As;
    const char* bB0 = (const char*)Bs;
#pragma unroll
    for (int n = 0; n < 4; ++n)
#pragma unroll
      for (int s = 0; s < 2; ++s)
        bh[0][n][s] = *(const bf16x8*)(bB0 + ((rbB + n * 2048) ^ (s * 64)));
#pragma unroll
    for (int mm = 0; mm < 2; ++mm)
#pragma unroll
      for (int s = 0; s < 2; ++s)
        av[0][mm][s] = *(const bf16x8*)(aB0 + ((rbA + mm * 2048) ^ (s * 64)));
  }

#pragma unroll 2
  for (int tt = 0; tt < NT; ++tt) {
    const char* aBuf = (const char*)As + (tt & 1) * 32768;

#pragma unroll
    for (int q = 0; q < 4; ++q) {
      // --- MFMA on operands issued >= 1 phase ago (no setprio: m190) ---
#pragma unroll
      for (int s = 0; s < 2; ++s)
#pragma unroll
        for (int mm = 0; mm < 2; ++mm)
#pragma unroll
          for (int n = 0; n < 4; ++n)
            acc[2 * q + mm][n] = __builtin_amdgcn_mfma_f32_16x16x32_bf16(
                av[q & 1][mm][s], bh[tt & 1][n][s], acc[2 * q + mm][n], 0, 0, 0);

      // --- stage A(t+1) both halves at q0 (WAR-safe: q3-end barrier of t-1
      // proved all waves consumed their av(t-1) reads) ---
      if (q == 0 && tt + 1 < NT) {
        STAGE(aG, As, tt + 1, 0);
        STAGE(aG, As, tt + 1, 1);
      }

      // --- prefetch next phase's A frags (same parity; stages write other) ---
      if (q < 3) {
#pragma unroll
        for (int mm = 0; mm < 2; ++mm)
#pragma unroll
          for (int s = 0; s < 2; ++s)
            av[(q + 1) & 1][mm][s] = *(const bf16x8*)(
                aBuf + ((rbA + (2 * (q + 1) + mm) * 2048) ^ (s * 64)));
      }

      if (q == 2) {
        // q2-end checkpoint: drain B(t+1) (issued t-1 q3) and A(t+1) (q0) ->
        // both older than HBM latency. Barrier publishes; cross-reads issue
        // HERE and hide under q3's MFMA.
        asm volatile("s_waitcnt vmcnt(0)" ::: "memory");
        __builtin_amdgcn_s_barrier();
        __builtin_amdgcn_sched_barrier(0);
        if (tt + 1 < NT) {
          const char* aN = (const char*)As + ((tt + 1) & 1) * 32768;
          const char* bN = (const char*)Bs + ((tt + 1) & 1) * 32768;
#pragma unroll
          for (int n = 0; n < 4; ++n)
#pragma unroll
            for (int s = 0; s < 2; ++s)
              bh[(tt + 1) & 1][n][s] =
                  *(const bf16x8*)(bN + ((rbB + n * 2048) ^ (s * 64)));
#pragma unroll
          for (int mm = 0; mm < 2; ++mm)
#pragma unroll
            for (int s = 0; s < 2; ++s)
              av[0][mm][s] = *(const bf16x8*)(aN + ((rbA + mm * 2048) ^ (s * 64)));
        }
      }

      if (q == 3) {
        // Stage B(t+2) both halves: q2-end barrier proved all waves executed
        // q0 -> every bh(t) read completed -> overwriting B parity is safe.
        if (tt + 2 < NT) {
          STAGE(bG, Bs, tt + 2, 0);
          STAGE(bG, Bs, tt + 2, 1);
        }
        __builtin_amdgcn_s_barrier();   // q3-end: closes the tile
      }
    }
  }
#undef STAGE

  // Epilogue: C/D layout col=lane&15, row=(lane>>4)*4+reg (m89-verified).
#pragma unroll
  for (int n = 0; n < 4; ++n) {
    int ncol = n0 + wc * 64 + n * 16 + lr;
    float bz = bias[ncol];
#pragma unroll
    for (int m = 0; m < 8; ++m) {
      int mrow = m0 + wr * 128 + m * 16 + kq * 4;
#pragma unroll
      for (int r = 0; r < 4; ++r)
        C[(size_t)(mrow + r) * N_TOT + ncol] = acc[m][n][r] + bz;
    }
  }
}

extern "C" void kernel_launch(void* const* d_in, const int* in_sizes, int n_in,
                              void* d_out, int out_size, void* d_ws, size_t ws_size,
                              hipStream_t stream) {
  const float* x       = (const float*)d_in[0];
  const int*   qweight = (const int*)d_in[1];
  const int*   qzeros  = (const int*)d_in[2];
  const float* scales  = (const float*)d_in[3];
  const float* bias    = (const float*)d_in[4];
  float* out = (float*)d_out;

  const size_t xb_bytes = (size_t)M_TOT * K_TOT * 2;   // 64 MB
  const size_t wt_bytes = (size_t)N_TOT * K_TOT * 2;   // 32 MB
  if (ws_size < xb_bytes + wt_bytes) return;

  unsigned short* Xb = (unsigned short*)d_ws;
  unsigned short* Wt = (unsigned short*)((char*)d_ws + xb_bytes);

  cvt_x_kernel<<<2048, 256, 0, stream>>>(x, Xb, M_TOT * K_TOT);
  dequant_lds_kernel<<<2048, 256, 0, stream>>>(qweight, qzeros, scales, Wt);

  dim3 grid((M_TOT / 256) * (N_TOT / 256));  // 512
  gemm_hoist_kernel<<<grid, 512, 0, stream>>>(Xb, Wt, bias, out);
}

// Round 23
// 264.851 us; speedup vs baseline: 1.0620x; 1.0129x over previous
//
#include <hip/hip_runtime.h>
#include <hip/hip_bf16.h>
#include <stdint.h>

// GPTQ 4-bit linear: y = x @ dequant(qweight,qzeros,scales) + bias
// x: [4,2048,4096] fp32 -> M=8192 rows; qweight [512,4096] i32 (8 k-nibbles/word);
// qzeros [32,512] i32 (8 n-nibbles/word, z=nib+1); scales [32,4096] f32; out f32.
//
// Configuration = round-22 champion (268.3 us), plus float4 epilogue via MFMA
// operand swap: mfma(bh, av) makes reg-dim span 4 consecutive n-cols
// (reg follows A-operand, lane&15 follows B-operand -- m89 layout algebra),
// so C-writes become dwordx4 (4x fewer store instrs, same bytes).

#define M_TOT 8192
#define N_TOT 4096
#define K_TOT 4096
#define NT    (K_TOT / 64)   // 64 K-tiles of BK=64

using bf16x8 = __attribute__((ext_vector_type(8))) __bf16;
using f32x4  = __attribute__((ext_vector_type(4))) float;

__device__ __forceinline__ unsigned short f2bf(float f) {
  unsigned u = __builtin_bit_cast(unsigned, f);
  u += 0x7fffu + ((u >> 16) & 1u);   // RNE
  return (unsigned short)(u >> 16);
}

// ---------------- x: fp32 -> bf16 (BW-floor, frozen) ----------------
__global__ void cvt_x_kernel(const float* __restrict__ x,
                             unsigned short* __restrict__ xb, int n) {
  int stride = gridDim.x * blockDim.x * 8;
  for (int i = (blockIdx.x * blockDim.x + threadIdx.x) * 8; i < n; i += stride) {
    float4 a = *reinterpret_cast<const float4*>(x + i);
    float4 b = *reinterpret_cast<const float4*>(x + i + 4);
    unsigned short o[8] = {f2bf(a.x), f2bf(a.y), f2bf(a.z), f2bf(a.w),
                           f2bf(b.x), f2bf(b.y), f2bf(b.z), f2bf(b.w)};
    *reinterpret_cast<uint4*>(xb + i) = *reinterpret_cast<const uint4*>(o);
  }
}

// ---- dequant -> W^T [N][K] bf16, LDS-transposed (r19-verified, frozen) -----
__global__ __launch_bounds__(256) void dequant_lds_kernel(
    const int* __restrict__ qweight, const int* __restrict__ qzeros,
    const float* __restrict__ scales, unsigned short* __restrict__ wt) {
  __shared__ int      lw[16][65];   // +1 pad: conflict-free transposed reads
  __shared__ float    lsc[64];
  __shared__ unsigned lzw[8];

  int db = blockIdx.x;              // 2048 blocks: 32 kw-tiles x 64 nn-tiles
  int kt = db >> 6, nt = db & 63;
  int kw0 = kt * 16, nn0 = nt * 64;
  int tau = threadIdx.x;

  int col = tau & 63, rowb = tau >> 6;       // rowb 0..3
#pragma unroll
  for (int r = 0; r < 4; ++r)
    lw[rowb + r * 4][col] = qweight[(kw0 + rowb + r * 4) * N_TOT + nn0 + col];
  int g = kt;                                // group = kw0/16 (GROUPSIZE 128)
  if (tau < 64) lsc[tau] = scales[g * N_TOT + nn0 + tau];
  if (tau < 8)  lzw[tau] = (unsigned)qzeros[g * (N_TOT / 8) + (nn0 >> 3) + tau];
  __syncthreads();

  int kwc = tau & 15, grp = tau >> 4;        // grp 0..15
#pragma unroll
  for (int j = 0; j < 4; ++j) {
    int nnr = grp * 4 + j;                   // 0..63
    unsigned w = (unsigned)lw[kwc][nnr];
    float sc = lsc[nnr];
    unsigned zw = lzw[nnr >> 3];
    float zs = sc * (float)(((zw >> ((nnr & 7) * 4)) & 15u) + 1u);
    unsigned short o[8];
#pragma unroll
    for (int jj = 0; jj < 8; ++jj) {
      float v = sc * (float)((w >> (4 * jj)) & 15u) - zs;
      o[jj] = f2bf(v);
    }
    *reinterpret_cast<uint4*>(wt + (size_t)(nn0 + nnr) * K_TOT +
                              (kw0 + kwc) * 8) =
        *reinterpret_cast<const uint4*>(o);
  }
}

// -- 256x256 GEMM (r17 structure, no setprio, swapped-operand epilogue) ------
__device__ __forceinline__ void gll16(const unsigned short* g, const unsigned short* l) {
  __builtin_amdgcn_global_load_lds(
      (const __attribute__((address_space(1))) void*)(uintptr_t)g,
      (__attribute__((address_space(3))) void*)(uintptr_t)l, 16, 0, 0);
}

__global__ __launch_bounds__(512, 2) void gemm_hoist_kernel(
    const unsigned short* __restrict__ A,   // [M_TOT][K_TOT] bf16
    const unsigned short* __restrict__ B,   // [N_TOT][K_TOT] bf16 (W^T)
    const float* __restrict__ bias,
    float* __restrict__ C) {
  __shared__ __align__(16) unsigned short As[2 * 256 * 64];   // 64 KB
  __shared__ __align__(16) unsigned short Bs[2 * 256 * 64];   // 64 KB

  int bid = blockIdx.x;                    // 512 blocks, 512 % 8 == 0
  int swz = (bid & 7) * 64 + (bid >> 3);   // bijective XCD swizzle (T1)
  int bm = swz & 31, bn = swz >> 5;        // 32 x 16 tiles
  int m0 = bm * 256, n0 = bn * 256;

  int t = threadIdx.x;
  int lane = t & 63;
  int wave = t >> 6;                       // 8 waves
  int wr = wave >> 2, wc = wave & 3;       // 2 (M) x 4 (N)
  int lr = lane & 15, kq = lane >> 4;

  // Staging (round-3 verified, 0 conflicts): physical chunk p = t&7 of rows
  // rowL0, rowL0+64; source pre-permuted j_log = (t&7) ^ (rowL0&7).
  int rowL0 = t >> 3;
  int jlog  = ((t & 7) ^ (rowL0 & 7)) * 8;
  const unsigned short* aG = A + (size_t)(m0 + rowL0) * K_TOT + jlog;
  const unsigned short* bG = B + (size_t)(n0 + rowL0) * K_TOT + jlog;

  // Swizzled read bases; s half-select composed with XOR (round-2 lesson).
  unsigned rbA = (unsigned)((wr * 128 + lr) * 128 + ((kq * 16) ^ ((lr & 7) << 4)));
  unsigned rbB = (unsigned)((wc * 64  + lr) * 128 + ((kq * 16) ^ ((lr & 7) << 4)));

  f32x4 acc[8][4] = {};
  bf16x8 av[2][2][2];   // [pingpong][mm][s]
  bf16x8 bh[2][4][2];   // [tile parity][n][s]

#define STAGE(matG, ldsArr, tile, h)                                              \
  do {                                                                            \
    const unsigned short* _g = (matG) + (size_t)(h) * 128 * K_TOT +               \
                               (size_t)(tile) * 64;                               \
    const unsigned short* _l = (ldsArr) + ((tile) & 1) * 16384 + (h) * 8192 +     \
                               t * 8;                                             \
    gll16(_g, _l);                                                                \
    gll16(_g + (size_t)64 * K_TOT, _l + 4096);                                    \
  } while (0)

  // Prologue: A(0):4, B(0):4, B(1):4 glls. A(1) stages at tile-0 q0.
  STAGE(aG, As, 0, 0);
  STAGE(aG, As, 0, 1);
  STAGE(bG, Bs, 0, 0);
  STAGE(bG, Bs, 0, 1);
  STAGE(bG, Bs, 1, 0);
  STAGE(bG, Bs, 1, 1);
  asm volatile("s_waitcnt vmcnt(4)" ::: "memory");  // A(0),B(0) landed
  __builtin_amdgcn_s_barrier();
  __builtin_amdgcn_sched_barrier(0);

  // Preload tile-0 operands: bh[0] = B(0), av[0] = A(0) phase-0 frags.
  {
    const char* aB0 = (const char*)As;
    const char* bB0 = (const char*)Bs;
#pragma unroll
    for (int n = 0; n < 4; ++n)
#pragma unroll
      for (int s = 0; s < 2; ++s)
        bh[0][n][s] = *(const bf16x8*)(bB0 + ((rbB + n * 2048) ^ (s * 64)));
#pragma unroll
    for (int mm = 0; mm < 2; ++mm)
#pragma unroll
      for (int s = 0; s < 2; ++s)
        av[0][mm][s] = *(const bf16x8*)(aB0 + ((rbA + mm * 2048) ^ (s * 64)));
  }

#pragma unroll 2
  for (int tt = 0; tt < NT; ++tt) {
    const char* aBuf = (const char*)As + (tt & 1) * 32768;

#pragma unroll
    for (int q = 0; q < 4; ++q) {
      // --- MFMA, operands SWAPPED: reg-dim -> n (A-op = bh), lane&15 -> m ---
#pragma unroll
      for (int s = 0; s < 2; ++s)
#pragma unroll
        for (int mm = 0; mm < 2; ++mm)
#pragma unroll
          for (int n = 0; n < 4; ++n)
            acc[2 * q + mm][n] = __builtin_amdgcn_mfma_f32_16x16x32_bf16(
                bh[tt & 1][n][s], av[q & 1][mm][s], acc[2 * q + mm][n], 0, 0, 0);

      // --- stage A(t+1) both halves at q0 (WAR-safe: q3-end barrier of t-1
      // proved all waves consumed their av(t-1) reads) ---
      if (q == 0 && tt + 1 < NT) {
        STAGE(aG, As, tt + 1, 0);
        STAGE(aG, As, tt + 1, 1);
      }

      // --- prefetch next phase's A frags (same parity; stages write other) ---
      if (q < 3) {
#pragma unroll
        for (int mm = 0; mm < 2; ++mm)
#pragma unroll
          for (int s = 0; s < 2; ++s)
            av[(q + 1) & 1][mm][s] = *(const bf16x8*)(
                aBuf + ((rbA + (2 * (q + 1) + mm) * 2048) ^ (s * 64)));
      }

      if (q == 2) {
        // q2-end checkpoint: drain B(t+1) (issued t-1 q3) and A(t+1) (q0) ->
        // both older than HBM latency. Barrier publishes; cross-reads issue
        // HERE and hide under q3's MFMA.
        asm volatile("s_waitcnt vmcnt(0)" ::: "memory");
        __builtin_amdgcn_s_barrier();
        __builtin_amdgcn_sched_barrier(0);
        if (tt + 1 < NT) {
          const char* aN = (const char*)As + ((tt + 1) & 1) * 32768;
          const char* bN = (const char*)Bs + ((tt + 1) & 1) * 32768;
#pragma unroll
          for (int n = 0; n < 4; ++n)
#pragma unroll
            for (int s = 0; s < 2; ++s)
              bh[(tt + 1) & 1][n][s] =
                  *(const bf16x8*)(bN + ((rbB + n * 2048) ^ (s * 64)));
#pragma unroll
          for (int mm = 0; mm < 2; ++mm)
#pragma unroll
            for (int s = 0; s < 2; ++s)
              av[0][mm][s] = *(const bf16x8*)(aN + ((rbA + mm * 2048) ^ (s * 64)));
        }
      }

      if (q == 3) {
        // Stage B(t+2) both halves: q2-end barrier proved all waves executed
        // q0 -> every bh(t) read completed -> overwriting B parity is safe.
        if (tt + 2 < NT) {
          STAGE(bG, Bs, tt + 2, 0);
          STAGE(bG, Bs, tt + 2, 1);
        }
        __builtin_amdgcn_s_barrier();   // q3-end: closes the tile
      }
    }
  }
#undef STAGE

  // Epilogue (swapped layout): lane holds row m = base + lr, 4 consecutive
  // n-cols at n*16 + kq*4 + r -> dwordx4 stores, bias as aligned float4.
#pragma unroll
  for (int m = 0; m < 8; ++m) {
    int mrow = m0 + wr * 128 + m * 16 + lr;
    float* crow = C + (size_t)mrow * N_TOT + n0 + wc * 64 + kq * 4;
#pragma unroll
    for (int n = 0; n < 4; ++n) {
      f32x4 bz = *reinterpret_cast<const f32x4*>(
          &bias[n0 + wc * 64 + n * 16 + kq * 4]);
      f32x4 v = acc[m][n];
#pragma unroll
      for (int r = 0; r < 4; ++r) v[r] += bz[r];
      *reinterpret_cast<f32x4*>(crow + n * 16) = v;
    }
  }
}

extern "C" void kernel_launch(void* const* d_in, const int* in_sizes, int n_in,
                              void* d_out, int out_size, void* d_ws, size_t ws_size,
                              hipStream_t stream) {
  const float* x       = (const float*)d_in[0];
  const int*   qweight = (const int*)d_in[1];
  const int*   qzeros  = (const int*)d_in[2];
  const float* scales  = (const float*)d_in[3];
  const float* bias    = (const float*)d_in[4];
  float* out = (float*)d_out;

  const size_t xb_bytes = (size_t)M_TOT * K_TOT * 2;   // 64 MB
  const size_t wt_bytes = (size_t)N_TOT * K_TOT * 2;   // 32 MB
  if (ws_size < xb_bytes + wt_bytes) return;

  unsigned short* Xb = (unsigned short*)d_ws;
  unsigned short* Wt = (unsigned short*)((char*)d_ws + xb_bytes);

  cvt_x_kernel<<<2048, 256, 0, stream>>>(x, Xb, M_TOT * K_TOT);
  dequant_lds_kernel<<<2048, 256, 0, stream>>>(qweight, qzeros, scales, Wt);

  dim3 grid((M_TOT / 256) * (N_TOT / 256));  // 512
  gemm_hoist_kernel<<<grid, 512, 0, stream>>>(Xb, Wt, bias, out);
}

// Round 24
// 264.146 us; speedup vs baseline: 1.0648x; 1.0027x over previous
//
#include <hip/hip_runtime.h>
#include <hip/hip_bf16.h>
#include <stdint.h>

// GPTQ 4-bit linear: y = x @ dequant(qweight,qzeros,scales) + bias
// x: [4,2048,4096] fp32 -> M=8192 rows; qweight [512,4096] i32 (8 k-nibbles/word);
// qzeros [32,512] i32 (8 n-nibbles/word, z=nib+1); scales [32,4096] f32; out f32.
//
// Configuration = round-23 champion (264.9 us), plus precomputed XOR-variant
// read bases: (rb + c*2048) ^ (s*64) == (rb ^ (s*64)) + c*2048 (bit 6 of rb is
// swizzle-only; c*2048 touches bits >=11) -> every fragment read becomes
// ds_read base+immediate, removing per-read address VALU.

#define M_TOT 8192
#define N_TOT 4096
#define K_TOT 4096
#define NT    (K_TOT / 64)   // 64 K-tiles of BK=64

using bf16x8 = __attribute__((ext_vector_type(8))) __bf16;
using f32x4  = __attribute__((ext_vector_type(4))) float;

__device__ __forceinline__ unsigned short f2bf(float f) {
  unsigned u = __builtin_bit_cast(unsigned, f);
  u += 0x7fffu + ((u >> 16) & 1u);   // RNE
  return (unsigned short)(u >> 16);
}

// ---------------- x: fp32 -> bf16 (BW-floor, frozen) ----------------
__global__ void cvt_x_kernel(const float* __restrict__ x,
                             unsigned short* __restrict__ xb, int n) {
  int stride = gridDim.x * blockDim.x * 8;
  for (int i = (blockIdx.x * blockDim.x + threadIdx.x) * 8; i < n; i += stride) {
    float4 a = *reinterpret_cast<const float4*>(x + i);
    float4 b = *reinterpret_cast<const float4*>(x + i + 4);
    unsigned short o[8] = {f2bf(a.x), f2bf(a.y), f2bf(a.z), f2bf(a.w),
                           f2bf(b.x), f2bf(b.y), f2bf(b.z), f2bf(b.w)};
    *reinterpret_cast<uint4*>(xb + i) = *reinterpret_cast<const uint4*>(o);
  }
}

// ---- dequant -> W^T [N][K] bf16, LDS-transposed (r19-verified, frozen) -----
__global__ __launch_bounds__(256) void dequant_lds_kernel(
    const int* __restrict__ qweight, const int* __restrict__ qzeros,
    const float* __restrict__ scales, unsigned short* __restrict__ wt) {
  __shared__ int      lw[16][65];   // +1 pad: conflict-free transposed reads
  __shared__ float    lsc[64];
  __shared__ unsigned lzw[8];

  int db = blockIdx.x;              // 2048 blocks: 32 kw-tiles x 64 nn-tiles
  int kt = db >> 6, nt = db & 63;
  int kw0 = kt * 16, nn0 = nt * 64;
  int tau = threadIdx.x;

  int col = tau & 63, rowb = tau >> 6;       // rowb 0..3
#pragma unroll
  for (int r = 0; r < 4; ++r)
    lw[rowb + r * 4][col] = qweight[(kw0 + rowb + r * 4) * N_TOT + nn0 + col];
  int g = kt;                                // group = kw0/16 (GROUPSIZE 128)
  if (tau < 64) lsc[tau] = scales[g * N_TOT + nn0 + tau];
  if (tau < 8)  lzw[tau] = (unsigned)qzeros[g * (N_TOT / 8) + (nn0 >> 3) + tau];
  __syncthreads();

  int kwc = tau & 15, grp = tau >> 4;        // grp 0..15
#pragma unroll
  for (int j = 0; j < 4; ++j) {
    int nnr = grp * 4 + j;                   // 0..63
    unsigned w = (unsigned)lw[kwc][nnr];
    float sc = lsc[nnr];
    unsigned zw = lzw[nnr >> 3];
    float zs = sc * (float)(((zw >> ((nnr & 7) * 4)) & 15u) + 1u);
    unsigned short o[8];
#pragma unroll
    for (int jj = 0; jj < 8; ++jj) {
      float v = sc * (float)((w >> (4 * jj)) & 15u) - zs;
      o[jj] = f2bf(v);
    }
    *reinterpret_cast<uint4*>(wt + (size_t)(nn0 + nnr) * K_TOT +
                              (kw0 + kwc) * 8) =
        *reinterpret_cast<const uint4*>(o);
  }
}

// -- 256x256 GEMM (r23 champion + immediate-offset fragment reads) -----------
__device__ __forceinline__ void gll16(const unsigned short* g, const unsigned short* l) {
  __builtin_amdgcn_global_load_lds(
      (const __attribute__((address_space(1))) void*)(uintptr_t)g,
      (__attribute__((address_space(3))) void*)(uintptr_t)l, 16, 0, 0);
}

__global__ __launch_bounds__(512, 2) void gemm_hoist_kernel(
    const unsigned short* __restrict__ A,   // [M_TOT][K_TOT] bf16
    const unsigned short* __restrict__ B,   // [N_TOT][K_TOT] bf16 (W^T)
    const float* __restrict__ bias,
    float* __restrict__ C) {
  __shared__ __align__(16) unsigned short As[2 * 256 * 64];   // 64 KB
  __shared__ __align__(16) unsigned short Bs[2 * 256 * 64];   // 64 KB

  int bid = blockIdx.x;                    // 512 blocks, 512 % 8 == 0
  int swz = (bid & 7) * 64 + (bid >> 3);   // bijective XCD swizzle (T1)
  int bm = swz & 31, bn = swz >> 5;        // 32 x 16 tiles
  int m0 = bm * 256, n0 = bn * 256;

  int t = threadIdx.x;
  int lane = t & 63;
  int wave = t >> 6;                       // 8 waves
  int wr = wave >> 2, wc = wave & 3;       // 2 (M) x 4 (N)
  int lr = lane & 15, kq = lane >> 4;

  // Staging (round-3 verified, 0 conflicts): physical chunk p = t&7 of rows
  // rowL0, rowL0+64; source pre-permuted j_log = (t&7) ^ (rowL0&7).
  int rowL0 = t >> 3;
  int jlog  = ((t & 7) ^ (rowL0 & 7)) * 8;
  const unsigned short* aG = A + (size_t)(m0 + rowL0) * K_TOT + jlog;
  const unsigned short* bG = B + (size_t)(n0 + rowL0) * K_TOT + jlog;

  // Swizzled read bases, both s-variants precomputed (bit-6 identity):
  // (rb + c*2048) ^ (s*64) == (rb ^ (s*64)) + c*2048.
  unsigned rbA = (unsigned)((wr * 128 + lr) * 128 + ((kq * 16) ^ ((lr & 7) << 4)));
  unsigned rbB = (unsigned)((wc * 64  + lr) * 128 + ((kq * 16) ^ ((lr & 7) << 4)));
  unsigned rbAs[2] = {rbA, rbA ^ 64u};
  unsigned rbBs[2] = {rbB, rbB ^ 64u};

  f32x4 acc[8][4] = {};
  bf16x8 av[2][2][2];   // [pingpong][mm][s]
  bf16x8 bh[2][4][2];   // [tile parity][n][s]

#define STAGE(matG, ldsArr, tile, h)                                              \
  do {                                                                            \
    const unsigned short* _g = (matG) + (size_t)(h) * 128 * K_TOT +               \
                               (size_t)(tile) * 64;                               \
    const unsigned short* _l = (ldsArr) + ((tile) & 1) * 16384 + (h) * 8192 +     \
                               t * 8;                                             \
    gll16(_g, _l);                                                                \
    gll16(_g + (size_t)64 * K_TOT, _l + 4096);                                    \
  } while (0)

  // Prologue: A(0):4, B(0):4, B(1):4 glls. A(1) stages at tile-0 q0.
  STAGE(aG, As, 0, 0);
  STAGE(aG, As, 0, 1);
  STAGE(bG, Bs, 0, 0);
  STAGE(bG, Bs, 0, 1);
  STAGE(bG, Bs, 1, 0);
  STAGE(bG, Bs, 1, 1);
  asm volatile("s_waitcnt vmcnt(4)" ::: "memory");  // A(0),B(0) landed
  __builtin_amdgcn_s_barrier();
  __builtin_amdgcn_sched_barrier(0);

  // Preload tile-0 operands: bh[0] = B(0), av[0] = A(0) phase-0 frags.
  {
    const char* aB0 = (const char*)As;
    const char* bB0 = (const char*)Bs;
#pragma unroll
    for (int n = 0; n < 4; ++n)
#pragma unroll
      for (int s = 0; s < 2; ++s)
        bh[0][n][s] = *(const bf16x8*)(bB0 + rbBs[s] + n * 2048);
#pragma unroll
    for (int mm = 0; mm < 2; ++mm)
#pragma unroll
      for (int s = 0; s < 2; ++s)
        av[0][mm][s] = *(const bf16x8*)(aB0 + rbAs[s] + mm * 2048);
  }

#pragma unroll 2
  for (int tt = 0; tt < NT; ++tt) {
    const char* aBuf = (const char*)As + (tt & 1) * 32768;

#pragma unroll
    for (int q = 0; q < 4; ++q) {
      // --- MFMA, operands swapped: reg-dim -> n, lane&15 -> m (r23) ---
#pragma unroll
      for (int s = 0; s < 2; ++s)
#pragma unroll
        for (int mm = 0; mm < 2; ++mm)
#pragma unroll
          for (int n = 0; n < 4; ++n)
            acc[2 * q + mm][n] = __builtin_amdgcn_mfma_f32_16x16x32_bf16(
                bh[tt & 1][n][s], av[q & 1][mm][s], acc[2 * q + mm][n], 0, 0, 0);

      // --- stage A(t+1) both halves at q0 (WAR-safe: q3-end barrier of t-1
      // proved all waves consumed their av(t-1) reads) ---
      if (q == 0 && tt + 1 < NT) {
        STAGE(aG, As, tt + 1, 0);
        STAGE(aG, As, tt + 1, 1);
      }

      // --- prefetch next phase's A frags (same parity; stages write other) ---
      if (q < 3) {
#pragma unroll
        for (int mm = 0; mm < 2; ++mm)
#pragma unroll
          for (int s = 0; s < 2; ++s)
            av[(q + 1) & 1][mm][s] = *(const bf16x8*)(
                aBuf + rbAs[s] + (2 * (q + 1) + mm) * 2048);
      }

      if (q == 2) {
        // q2-end checkpoint: drain B(t+1) (issued t-1 q3) and A(t+1) (q0) ->
        // both older than HBM latency. Barrier publishes; cross-reads issue
        // HERE and hide under q3's MFMA.
        asm volatile("s_waitcnt vmcnt(0)" ::: "memory");
        __builtin_amdgcn_s_barrier();
        __builtin_amdgcn_sched_barrier(0);
        if (tt + 1 < NT) {
          const char* aN = (const char*)As + ((tt + 1) & 1) * 32768;
          const char* bN = (const char*)Bs + ((tt + 1) & 1) * 32768;
#pragma unroll
          for (int n = 0; n < 4; ++n)
#pragma unroll
            for (int s = 0; s < 2; ++s)
              bh[(tt + 1) & 1][n][s] =
                  *(const bf16x8*)(bN + rbBs[s] + n * 2048);
#pragma unroll
          for (int mm = 0; mm < 2; ++mm)
#pragma unroll
            for (int s = 0; s < 2; ++s)
              av[0][mm][s] = *(const bf16x8*)(aN + rbAs[s] + mm * 2048);
        }
      }

      if (q == 3) {
        // Stage B(t+2) both halves: q2-end barrier proved all waves executed
        // q0 -> every bh(t) read completed -> overwriting B parity is safe.
        if (tt + 2 < NT) {
          STAGE(bG, Bs, tt + 2, 0);
          STAGE(bG, Bs, tt + 2, 1);
        }
        __builtin_amdgcn_s_barrier();   // q3-end: closes the tile
      }
    }
  }
#undef STAGE

  // Epilogue (swapped layout): lane holds row m = base + lr, 4 consecutive
  // n-cols at n*16 + kq*4 + r -> dwordx4 stores, bias as aligned float4.
#pragma unroll
  for (int m = 0; m < 8; ++m) {
    int mrow = m0 + wr * 128 + m * 16 + lr;
    float* crow = C + (size_t)mrow * N_TOT + n0 + wc * 64 + kq * 4;
#pragma unroll
    for (int n = 0; n < 4; ++n) {
      f32x4 bz = *reinterpret_cast<const f32x4*>(
          &bias[n0 + wc * 64 + n * 16 + kq * 4]);
      f32x4 v = acc[m][n];
#pragma unroll
      for (int r = 0; r < 4; ++r) v[r] += bz[r];
      *reinterpret_cast<f32x4*>(crow + n * 16) = v;
    }
  }
}

extern "C" void kernel_launch(void* const* d_in, const int* in_sizes, int n_in,
                              void* d_out, int out_size, void* d_ws, size_t ws_size,
                              hipStream_t stream) {
  const float* x       = (const float*)d_in[0];
  const int*   qweight = (const int*)d_in[1];
  const int*   qzeros  = (const int*)d_in[2];
  const float* scales  = (const float*)d_in[3];
  const float* bias    = (const float*)d_in[4];
  float* out = (float*)d_out;

  const size_t xb_bytes = (size_t)M_TOT * K_TOT * 2;   // 64 MB
  const size_t wt_bytes = (size_t)N_TOT * K_TOT * 2;   // 32 MB
  if (ws_size < xb_bytes + wt_bytes) return;

  unsigned short* Xb = (unsigned short*)d_ws;
  unsigned short* Wt = (unsigned short*)((char*)d_ws + xb_bytes);

  cvt_x_kernel<<<2048, 256, 0, stream>>>(x, Xb, M_TOT * K_TOT);
  dequant_lds_kernel<<<2048, 256, 0, stream>>>(qweight, qzeros, scales, Wt);

  dim3 grid((M_TOT / 256) * (N_TOT / 256));  // 512
  gemm_hoist_kernel<<<grid, 512, 0, stream>>>(Xb, Wt, bias, out);
}